// Round 9
// baseline (1043.433 us; speedup 1.0000x reference)
//
#include <hip/hip_runtime.h>
#include <hip/hip_bf16.h>
#include <stdint.h>

#define T_TOK 8192
#define CDIM  1024
#define HDIM  4096
#define NEXP  8
#define TOPK_ 2
#define GT_MAX 136         // grouped 128-row tiles upper bound (<=128+7)
#define UT_MAX 200         // grouped + 64 dense tiles
#define GROWS_MAX (GT_MAX * 128)

typedef __attribute__((ext_vector_type(8))) short short8;
typedef __attribute__((ext_vector_type(4))) float f32x4;

__device__ __forceinline__ void gload16(const short* g, short* l) {
  __builtin_amdgcn_global_load_lds(
      (const __attribute__((address_space(1))) unsigned int*)(g),
      (__attribute__((address_space(3))) unsigned int*)(l), 16, 0, 0);
}

// ---------------- gate phase A ----------------
__global__ __launch_bounds__(256) void gate_kernel(
    const float* __restrict__ x, const float* __restrict__ gw,
    int* __restrict__ tokinfo, float* __restrict__ tokw,
    int* __restrict__ bcnt, float* __restrict__ spart)
{
  const int wid = threadIdx.x >> 6, lane = threadIdx.x & 63;
  const int t = blockIdx.x * 4 + wid;
  float acc[NEXP];
#pragma unroll
  for (int e = 0; e < NEXP; ++e) acc[e] = 0.f;
  const float4* xr = (const float4*)x + (size_t)t * (CDIM / 4);
  const float4* gw4 = (const float4*)gw;
#pragma unroll
  for (int i = 0; i < CDIM / 256; ++i) {
    const float4 xv = xr[lane + 64 * i];
#pragma unroll
    for (int e = 0; e < NEXP; ++e) {
      const float4 gv = gw4[e * (CDIM / 4) + lane + 64 * i];
      acc[e] += xv.x * gv.x + xv.y * gv.y + xv.z * gv.z + xv.w * gv.w;
    }
  }
#pragma unroll
  for (int off = 32; off > 0; off >>= 1) {
#pragma unroll
    for (int e = 0; e < NEXP; ++e) acc[e] += __shfl_xor(acc[e], off);
  }
  float mx = acc[0];
#pragma unroll
  for (int e = 1; e < NEXP; ++e) mx = fmaxf(mx, acc[e]);
  float p[NEXP]; float s = 0.f;
#pragma unroll
  for (int e = 0; e < NEXP; ++e) { p[e] = __expf(acc[e] - mx); s += p[e]; }
  const float inv = 1.f / s;
#pragma unroll
  for (int e = 0; e < NEXP; ++e) p[e] *= inv;
  float v0 = p[0]; int i0 = 0;
#pragma unroll
  for (int e = 1; e < NEXP; ++e) if (p[e] > v0) { v0 = p[e]; i0 = e; }
  float v1 = -1.f; int i1 = 0;
#pragma unroll
  for (int e = 0; e < NEXP; ++e) if (e != i0 && p[e] > v1) { v1 = p[e]; i1 = e; }

  __shared__ float sp[4][NEXP];
  __shared__ int   se[4][2];
  __shared__ float swt[4][2];
  if (lane == 0) {
#pragma unroll
    for (int e = 0; e < NEXP; ++e) sp[wid][e] = p[e];
    const float wn = 1.f / (v0 + v1);
    se[wid][0] = i0; se[wid][1] = i1;
    swt[wid][0] = v0 * wn; swt[wid][1] = v1 * wn;
  }
  __syncthreads();
  if (threadIdx.x == 0) {
    int cnt[NEXP];
#pragma unroll
    for (int e = 0; e < NEXP; ++e) cnt[e] = 0;
#pragma unroll
    for (int tt = 0; tt < 4; ++tt) {
      const int e0 = se[tt][0], e1 = se[tt][1];
      const int r0 = cnt[e0]++; const int r1 = cnt[e1]++;
      tokinfo[blockIdx.x * 4 + tt] = e0 | (e1 << 3) | (r0 << 6) | (r1 << 10);
      ((float2*)tokw)[blockIdx.x * 4 + tt] = make_float2(swt[tt][0], swt[tt][1]);
    }
#pragma unroll
    for (int e = 0; e < NEXP; ++e) bcnt[blockIdx.x * NEXP + e] = cnt[e];
  }
  if (threadIdx.x < NEXP)
    spart[blockIdx.x * NEXP + threadIdx.x] =
        sp[0][threadIdx.x] + sp[1][threadIdx.x] + sp[2][threadIdx.x] + sp[3][threadIdx.x];
}

// ---------------- gate phase B: scan -> offsets, ecnt, 128-tile map, aux ----------------
__global__ __launch_bounds__(512) void scan_kernel(
    const int* __restrict__ bcnt, int* __restrict__ boff, int* __restrict__ ecnt,
    const float* __restrict__ spart, float* __restrict__ aux_out,
    int* __restrict__ pad_off, int* __restrict__ tile_map, int* __restrict__ ntiles)
{
  const int w = threadIdx.x >> 6, l = threadIdx.x & 63;
  int run = 0;
#pragma unroll 4
  for (int c = 0; c < (T_TOK / 4) / 64; ++c) {
    const int b = c * 64 + l;
    const int v = bcnt[b * NEXP + w];
    int sc = v;
#pragma unroll
    for (int off = 1; off < 64; off <<= 1) {
      const int t = __shfl_up(sc, off);
      if (l >= off) sc += t;
    }
    boff[b * NEXP + w] = run + sc - v;
    run += __shfl(sc, 63);
  }
  if (l == 0) ecnt[w] = run;
  float fs = 0.f;
  for (int c = 0; c < (T_TOK / 4) / 64; ++c) fs += spart[(c * 64 + l) * NEXP + w];
#pragma unroll
  for (int off = 32; off > 0; off >>= 1) fs += __shfl_xor(fs, off);
  __shared__ float pis[NEXP];
  __shared__ int cs[NEXP];
  if (l == 0) { pis[w] = fs; cs[w] = run; }
  __syncthreads();
  if (threadIdx.x == 0) {
    float aux = 0.f;
#pragma unroll
    for (int e = 0; e < NEXP; ++e) {
      const float Pi = pis[e] / (float)T_TOK;
      const float ce = (float)cs[e] / (float)(T_TOK * TOPK_);
      aux += Pi * ce * (float)NEXP;
    }
    aux_out[0] = aux * 0.01f;
    ecnt[8] = T_TOK;  // dense pseudo-expert
    int acc = 0, nt = 0;
    for (int e = 0; e < NEXP; ++e) {
      pad_off[e] = acc;
      const int te = (cs[e] + 127) >> 7;
      for (int t = 0; t < te; ++t) { tile_map[nt] = e | ((t * 128) << 4); ++nt; }
      acc += te * 128;
    }
    ntiles[0] = nt;
    for (int t = 0; t < T_TOK / 128; ++t) { tile_map[nt] = 8 | ((t * 128) << 4); ++nt; }
    ntiles[1] = nt;
  }
}

// ---------------- gate phase C: scatter into 128-padded concat list + tokpos ----------------
__global__ __launch_bounds__(256) void scatter_kernel(
    const int* __restrict__ tokinfo, const float* __restrict__ tokw,
    const int* __restrict__ boff, const int* __restrict__ pad_off,
    int* __restrict__ grows, float* __restrict__ gww, int2* __restrict__ tokpos)
{
  const int t = blockIdx.x * 256 + threadIdx.x;
  const int info = tokinfo[t];
  const int e0 = info & 7, e1 = (info >> 3) & 7;
  const int r0 = (info >> 6) & 15, r1 = (info >> 10) & 15;
  const int b = t >> 2;
  const float2 wv = ((const float2*)tokw)[t];
  const int g0 = pad_off[e0] + boff[b * NEXP + e0] + r0;
  grows[g0] = t; gww[g0] = wv.x;
  const int g1 = pad_off[e1] + boff[b * NEXP + e1] + r1;
  grows[g1] = t; gww[g1] = wv.y;
  tokpos[t] = make_int2(g0, g1);
}

// ---------------- x fp32 -> bf16 ----------------
__global__ __launch_bounds__(256) void cvt_x_kernel(const float* __restrict__ x,
                                                    __hip_bfloat16* __restrict__ xb)
{
  const int i = blockIdx.x * 256 + threadIdx.x;
  const float4 v = ((const float4*)x)[i];
  union { __hip_bfloat16 h[4]; uint2 u; } o;
  o.h[0] = __float2bfloat16(v.x); o.h[1] = __float2bfloat16(v.y);
  o.h[2] = __float2bfloat16(v.z); o.h[3] = __float2bfloat16(v.w);
  ((uint2*)xb)[i] = o.u;
}

// ---------------- batched transpose+convert ----------------
struct TD { const float* src; __hip_bfloat16* dst; int N; int nsh; int M; };
struct TB { TD d[27]; };
__global__ __launch_bounds__(256) void tbatch_kernel(TB tb)
{
  const int m = blockIdx.x >> 12;
  const int t = blockIdx.x & 4095;
  const TD td = tb.d[m];
  const int n0 = (t & ((1 << td.nsh) - 1)) << 5;
  const int m0 = (t >> td.nsh) << 5;
  __shared__ float tile[32][33];
  const int tx = threadIdx.x & 31, ty = threadIdx.x >> 5;
#pragma unroll
  for (int i = 0; i < 4; ++i)
    tile[ty + 8 * i][tx] = td.src[(size_t)(m0 + ty + 8 * i) * td.N + n0 + tx];
  __syncthreads();
#pragma unroll
  for (int i = 0; i < 4; ++i)
    td.dst[(size_t)(n0 + ty + 8 * i) * td.M + m0 + tx] = __float2bfloat16(tile[tx][ty + 8 * i]);
}

// ---------------- GEMM1: 128x128 tile, 256 thr, ring-4 64KB -> 2 blocks/CU ----------------
// B-tile = 128 rows = 64 h-cols x (G,U) interleaved at 16-col granules.
__global__ __launch_bounds__(256, 2) void gemm1_pipe_kernel(
    const __hip_bfloat16* __restrict__ Abase,
    const __hip_bfloat16* __restrict__ B0mat, const __hip_bfloat16* __restrict__ B1mat,
    __hip_bfloat16* __restrict__ midout,
    const int* __restrict__ rowlist, const int* __restrict__ ecnt,
    const int* __restrict__ tile_map, const int* __restrict__ ntiles,
    int mode, int tile_base)
{
  constexpr int K = CDIM;
  constexpr int NT = 32;
  __shared__ __align__(16) short lds[32768];   // A 16K shorts + B 16K shorts (64 KB)

  int ti = blockIdx.y + tile_base;
  if (mode == 2) ti += ntiles[0];
  const int hi = (mode == 1) ? ntiles[0] : ntiles[1];
  if (ti >= hi) return;
  const int tm = tile_map[ti];
  const int e = tm & 15, rb = tm >> 4;
  const int rows_valid = ecnt[e] - rb;
  const int gbmid = (int)blockIdx.y * 128;
  const int glist = ti * 128;

  const int t = threadIdx.x, l = t & 63, w = t >> 6;
  const int sr = t >> 2;                        // 0..63
  const int csrc = (t & 3) ^ ((t >> 3) & 3);
  const int n0h = blockIdx.x * 64;              // h-col base (64 h per block)

  int r0g, r1g;
  if (e == 8) { r0g = rb + sr; r1g = rb + 64 + sr; }
  else {
    const int c0 = sr < rows_valid ? sr : rows_valid - 1;
    const int c1 = (64 + sr) < rows_valid ? (64 + sr) : rows_valid - 1;
    r0g = rowlist[glist + c0]; r1g = rowlist[glist + c1];
  }
  const short* pA0 = (const short*)Abase + (size_t)r0g * K + csrc * 8;
  const short* pA1 = (const short*)Abase + (size_t)r1g * K + csrc * 8;
  // B rows 0..127: granule g=br>>4, s=g&1 (G/U), h = n0h + (g>>1)*16 + (br&15)
  const int br0 = sr, br1 = 64 + sr;
  const int s0 = (br0 >> 4) & 1, s1 = (br1 >> 4) & 1;
  const int h0 = n0h + (br0 >> 5) * 16 + (br0 & 15);
  const int h1 = n0h + (br1 >> 5) * 16 + (br1 & 15);
  const short* pB0 = (const short*)(s0 ? B1mat : B0mat) + (size_t)e * CDIM * HDIM + (size_t)h0 * K + csrc * 8;
  const short* pB1 = (const short*)(s1 ? B1mat : B0mat) + (size_t)e * CDIM * HDIM + (size_t)h1 * K + csrc * 8;

  short* dstA = lds + w * 512;
  short* dstB = lds + 16384 + w * 512;

  const int wr = w >> 1, wc = w & 1;            // 2x2 wave grid
  const int chunk = (((l >> 4) ^ ((l >> 1) & 3)) << 3);
  const int afb = (wr * 64 + (l & 15)) * 32 + chunk;
  const int bfb = (wc * 64 + (l & 15)) * 32 + chunk;

  f32x4 acc[4][4];
#pragma unroll
  for (int i = 0; i < 4; ++i)
#pragma unroll
    for (int j = 0; j < 4; ++j) acc[i][j] = (f32x4){0.f, 0.f, 0.f, 0.f};

#define STAGE_A(q) { const int o_ = ((q) & 3) * 4096; \
    gload16(pA0 + (q) * 32, dstA + o_); \
    gload16(pA1 + (q) * 32, dstA + o_ + 2048); }
#define STAGE_B(q) { const int o_ = ((q) & 3) * 4096; \
    gload16(pB0 + (q) * 32, dstB + o_); \
    gload16(pB1 + (q) * 32, dstB + o_ + 2048); }

  STAGE_A(0) STAGE_B(0) STAGE_A(1) STAGE_B(1)

  short8 af[4], bf[4];
  for (int q = 0; q < NT; ++q) {
    const int sA = (q & 3) * 4096, sB = 16384 + (q & 3) * 4096;
    // ledger: 4 loads/slot; outstanding q(4)+q+1(4)=8 -> vmcnt(4) completes slot q.
    if (q == NT - 1) {
      asm volatile("s_waitcnt vmcnt(0)\n\ts_barrier" ::: "memory");
    } else {
      asm volatile("s_waitcnt vmcnt(4)\n\ts_barrier" ::: "memory");
    }
    __builtin_amdgcn_sched_barrier(0);
    if (q + 2 < NT) STAGE_A(q + 2)
#pragma unroll
    for (int mi = 0; mi < 4; ++mi) af[mi] = *(const short8*)(lds + sA + afb + mi * 512);
#pragma unroll
    for (int ni = 0; ni < 4; ++ni) bf[ni] = *(const short8*)(lds + sB + bfb + ni * 512);
    __builtin_amdgcn_s_setprio(1);
#pragma unroll
    for (int mi = 0; mi < 2; ++mi)
#pragma unroll
      for (int ni = 0; ni < 4; ++ni)
        acc[mi][ni] = __builtin_amdgcn_mfma_f32_16x16x32_bf16(af[mi], bf[ni], acc[mi][ni], 0, 0, 0);
    __builtin_amdgcn_s_setprio(0);
    if (q + 2 < NT) STAGE_B(q + 2)
    __builtin_amdgcn_s_setprio(1);
#pragma unroll
    for (int mi = 2; mi < 4; ++mi)
#pragma unroll
      for (int ni = 0; ni < 4; ++ni)
        acc[mi][ni] = __builtin_amdgcn_mfma_f32_16x16x32_bf16(af[mi], bf[ni], acc[mi][ni], 0, 0, 0);
    __builtin_amdgcn_s_setprio(0);
  }
#undef STAGE_A
#undef STAGE_B

  const int rl = (l >> 4) * 4, cl = l & 15;
#pragma unroll
  for (int mi = 0; mi < 4; ++mi) {
#pragma unroll
    for (int j = 0; j < 4; ++j) {
      const int rlocal = wr * 64 + mi * 16 + rl + j;
      if (rlocal < rows_valid) {
        __hip_bfloat16* mp = midout + (size_t)(gbmid + rlocal) * HDIM;
#pragma unroll
        for (int jj = 0; jj < 2; ++jj) {
          const float g = acc[mi][jj * 2][j], u = acc[mi][jj * 2 + 1][j];
          const float sv = g / (1.f + __expf(-g));
          mp[n0h + (wc * 2 + jj) * 16 + cl] = __float2bfloat16(sv * u);
        }
      }
    }
  }
}

// ---------------- GEMM2: 128x128 tile, K=4096, ring-4 64KB -> 2 blocks/CU ----------------
template <int OST>
__global__ __launch_bounds__(256, 2) void gemm2_pipe_kernel(
    const __hip_bfloat16* __restrict__ mid, const __hip_bfloat16* __restrict__ wd9,
    float* __restrict__ mid2, float* __restrict__ y,
    const int* __restrict__ rowlist, const float* __restrict__ roww,
    const int* __restrict__ ecnt, const int* __restrict__ tile_map,
    const int* __restrict__ ntiles, const float* __restrict__ ssc,
    int mode, int tile_base)
{
  constexpr int K = HDIM;
  constexpr int NT = K / 32;                    // 128 K-steps
  __shared__ __align__(16) short lds[32768];

  int ti = blockIdx.y + tile_base;
  if (mode == 2) ti += ntiles[0];
  const int hi = (mode == 1) ? ntiles[0] : ntiles[1];
  if (ti >= hi) return;
  const int tm = tile_map[ti];
  const int e = tm & 15, rb = tm >> 4;
  const int rows_valid = ecnt[e] - rb;
  const int gbmid = (int)blockIdx.y * 128;
  const int glist = ti * 128;

  const int t = threadIdx.x, l = t & 63, w = t >> 6;
  const int sr = t >> 2;
  const int csrc = (t & 3) ^ ((t >> 3) & 3);
  const int n0 = blockIdx.x * 128;

  const short* pA0 = (const short*)mid + (size_t)(gbmid + sr) * K + csrc * 8;
  const short* pA1 = pA0 + (size_t)64 * K;
  const short* pB0 = (const short*)wd9 + (size_t)e * CDIM * HDIM + (size_t)(n0 + sr) * K + csrc * 8;
  const short* pB1 = pB0 + (size_t)64 * K;

  short* dstA = lds + w * 512;
  short* dstB = lds + 16384 + w * 512;

  const int wr = w >> 1, wc = w & 1;
  const int chunk = (((l >> 4) ^ ((l >> 1) & 3)) << 3);
  const int afb = (wr * 64 + (l & 15)) * 32 + chunk;
  const int bfb = (wc * 64 + (l & 15)) * 32 + chunk;

  f32x4 acc[4][4];
#pragma unroll
  for (int i = 0; i < 4; ++i)
#pragma unroll
    for (int j = 0; j < 4; ++j) acc[i][j] = (f32x4){0.f, 0.f, 0.f, 0.f};

#define S_A(q) { const int o_ = ((q) & 3) * 4096; \
    gload16(pA0 + (size_t)(q) * 32, dstA + o_); \
    gload16(pA1 + (size_t)(q) * 32, dstA + o_ + 2048); }
#define S_B(q) { const int o_ = ((q) & 3) * 4096; \
    gload16(pB0 + (size_t)(q) * 32, dstB + o_); \
    gload16(pB1 + (size_t)(q) * 32, dstB + o_ + 2048); }

  S_A(0) S_B(0) S_A(1) S_B(1)

  short8 af[4], bf[4];
  for (int q = 0; q < NT; ++q) {
    const int sA = (q & 3) * 4096, sB = 16384 + (q & 3) * 4096;
    if (q == NT - 1) {
      asm volatile("s_waitcnt vmcnt(0)\n\ts_barrier" ::: "memory");
    } else {
      asm volatile("s_waitcnt vmcnt(4)\n\ts_barrier" ::: "memory");
    }
    __builtin_amdgcn_sched_barrier(0);
    if (q + 2 < NT) S_A(q + 2)
#pragma unroll
    for (int mi = 0; mi < 4; ++mi) af[mi] = *(const short8*)(lds + sA + afb + mi * 512);
#pragma unroll
    for (int ni = 0; ni < 4; ++ni) bf[ni] = *(const short8*)(lds + sB + bfb + ni * 512);
    __builtin_amdgcn_s_setprio(1);
#pragma unroll
    for (int mi = 0; mi < 2; ++mi)
#pragma unroll
      for (int ni = 0; ni < 4; ++ni)
        acc[mi][ni] = __builtin_amdgcn_mfma_f32_16x16x32_bf16(af[mi], bf[ni], acc[mi][ni], 0, 0, 0);
    __builtin_amdgcn_s_setprio(0);
    if (q + 2 < NT) S_B(q + 2)
    __builtin_amdgcn_s_setprio(1);
#pragma unroll
    for (int mi = 2; mi < 4; ++mi)
#pragma unroll
      for (int ni = 0; ni < 4; ++ni)
        acc[mi][ni] = __builtin_amdgcn_mfma_f32_16x16x32_bf16(af[mi], bf[ni], acc[mi][ni], 0, 0, 0);
    __builtin_amdgcn_s_setprio(0);
  }
#undef S_A
#undef S_B

  const int rl = (l >> 4) * 4, cl = l & 15;
  if (OST) {
#pragma unroll
    for (int mi = 0; mi < 4; ++mi) {
#pragma unroll
      for (int j = 0; j < 4; ++j) {
        const int rlocal = wr * 64 + mi * 16 + rl + j;
        if (rlocal < rows_valid) {
          float* mp = mid2 + (size_t)(glist + rlocal) * CDIM + n0 + wc * 64 + cl;
#pragma unroll
          for (int ni = 0; ni < 4; ++ni) mp[ni * 16] = acc[mi][ni][j];
        }
      }
    }
  } else {
    const float ss = ssc[0];
#pragma unroll
    for (int mi = 0; mi < 4; ++mi) {
#pragma unroll
      for (int j = 0; j < 4; ++j) {
        const int rlocal = wr * 64 + mi * 16 + rl + j;
        if (rlocal < rows_valid) {
          int tok; float wgt;
          if (e == 8) { tok = rb + rlocal; wgt = ss; }
          else { tok = rowlist[glist + rlocal]; wgt = roww[glist + rlocal]; }
          float* yp = y + (size_t)tok * CDIM + n0 + wc * 64 + cl;
#pragma unroll
          for (int ni = 0; ni < 4; ++ni)
            unsafeAtomicAdd(yp + ni * 16, wgt * acc[mi][ni][j]);
        }
      }
    }
  }
}

// ---------------- combine: y[t] = ss*dense + w0*exp0 + w1*exp1 ----------------
__global__ __launch_bounds__(256) void combine_kernel(
    const float* __restrict__ mid2, const int* __restrict__ ntiles,
    const int2* __restrict__ tokpos, const float* __restrict__ tokw,
    const float* __restrict__ ssc, float* __restrict__ y)
{
  const int t = blockIdx.x;
  const int c = threadIdx.x * 4;
  const int dbase = ntiles[0] * 128;
  const int2 gp = tokpos[t];
  const float2 wv = ((const float2*)tokw)[t];
  const float ss = ssc[0];
  const float4 d = *(const float4*)(mid2 + (size_t)(dbase + t) * CDIM + c);
  const float4 a = *(const float4*)(mid2 + (size_t)gp.x * CDIM + c);
  const float4 b = *(const float4*)(mid2 + (size_t)gp.y * CDIM + c);
  float4 r;
  r.x = ss * d.x + wv.x * a.x + wv.y * b.x;
  r.y = ss * d.y + wv.x * a.y + wv.y * b.y;
  r.z = ss * d.z + wv.x * a.z + wv.y * b.z;
  r.w = ss * d.w + wv.x * a.w + wv.y * b.w;
  *(float4*)(y + (size_t)t * CDIM + c) = r;
}

// ---------------- host ----------------
extern "C" void kernel_launch(void* const* d_in, const int* in_sizes, int n_in,
                              void* d_out, int out_size, void* d_ws, size_t ws_size,
                              hipStream_t stream)
{
  const float* x   = (const float*)d_in[0];
  const float* gw  = (const float*)d_in[1];
  const float* wg  = (const float*)d_in[2];
  const float* wu  = (const float*)d_in[3];
  const float* wd  = (const float*)d_in[4];
  const float* swg = (const float*)d_in[5];
  const float* swu = (const float*)d_in[6];
  const float* swd = (const float*)d_in[7];
  const float* ssc = (const float*)d_in[8];
  float* y = (float*)d_out;

  auto al = [](size_t v) { return (v + 255) & ~(size_t)255; };
  char* ws = (char*)d_ws;
  size_t off = 0;
  __hip_bfloat16* xb = (__hip_bfloat16*)(ws + off); off += al((size_t)T_TOK * CDIM * 2);
  int*   tokinfo = (int*)(ws + off);   off += al((size_t)T_TOK * 4);
  float* tokw    = (float*)(ws + off); off += al((size_t)T_TOK * 8);
  int2*  tokpos  = (int2*)(ws + off);  off += al((size_t)T_TOK * 8);
  int*   bcnt    = (int*)(ws + off);   off += al((size_t)(T_TOK / 4) * NEXP * 4);
  int*   boffb   = (int*)(ws + off);   off += al((size_t)(T_TOK / 4) * NEXP * 4);
  float* spart   = (float*)(ws + off); off += al((size_t)(T_TOK / 4) * NEXP * 4);
  int*   ecnt    = (int*)(ws + off);   off += 256;   // 9 used
  int*   pad_off = (int*)(ws + off);   off += 256;
  int*   ntiles  = (int*)(ws + off);   off += 256;
  int*   tile_map= (int*)(ws + off);   off += al((size_t)UT_MAX * 4);
  int*   grows   = (int*)(ws + off);   off += al((size_t)GROWS_MAX * 4);
  float* gww     = (float*)(ws + off); off += al((size_t)GROWS_MAX * 4);

  const size_t WMAT = (size_t)CDIM * HDIM;
  __hip_bfloat16* wg9 = (__hip_bfloat16*)(ws + off); off += 9 * WMAT * 2;
  __hip_bfloat16* wu9 = (__hip_bfloat16*)(ws + off); off += 9 * WMAT * 2;
  __hip_bfloat16* wd9 = (__hip_bfloat16*)(ws + off); off += 9 * WMAT * 2;
  __hip_bfloat16* mid = (__hip_bfloat16*)(ws + off);
  const size_t mid_avail = (ws_size > off) ? (ws_size - off) : 0;
  const size_t TILE_B = (size_t)128 * HDIM * 2;                 // 1 MB per 128-row mid tile
  const size_t MIDB   = (size_t)UT_MAX * TILE_B;                // bf16 mid (full)
  const size_t MID2B  = (size_t)UT_MAX * 128 * CDIM * 4;        // fp32 partials

  gate_kernel<<<T_TOK / 4, 256, 0, stream>>>(x, gw, tokinfo, tokw, bcnt, spart);
  scan_kernel<<<1, 512, 0, stream>>>(bcnt, boffb, ecnt, spart, y + (size_t)T_TOK * CDIM,
                                     pad_off, tile_map, ntiles);
  scatter_kernel<<<T_TOK / 256, 256, 0, stream>>>(tokinfo, tokw, boffb, pad_off,
                                                  grows, gww, tokpos);
  cvt_x_kernel<<<T_TOK * CDIM / 4 / 256, 256, 0, stream>>>(x, xb);

  TB tb;
  for (int e = 0; e < 8; ++e) {
    tb.d[e]      = TD{wg + e * WMAT, wg9 + e * WMAT, HDIM, 7, CDIM};
    tb.d[8 + e]  = TD{wu + e * WMAT, wu9 + e * WMAT, HDIM, 7, CDIM};
    tb.d[16 + e] = TD{wd + e * WMAT, wd9 + e * WMAT, CDIM, 5, HDIM};
  }
  tb.d[24] = TD{swg, wg9 + 8 * WMAT, HDIM, 7, CDIM};
  tb.d[25] = TD{swu, wu9 + 8 * WMAT, HDIM, 7, CDIM};
  tb.d[26] = TD{swd, wd9 + 8 * WMAT, CDIM, 5, HDIM};
  tbatch_kernel<<<27 * 4096, 256, 0, stream>>>(tb);

  if (mid_avail >= MIDB + MID2B) {
    // STORE tier: unified gemm1, gemm2 plain stores, combine (no atomics anywhere)
    float* mid2 = (float*)((char*)mid + MIDB);
    gemm1_pipe_kernel<<<dim3(HDIM / 64, UT_MAX), 256, 0, stream>>>(
        xb, wg9, wu9, mid, grows, ecnt, tile_map, ntiles, 0, 0);
    gemm2_pipe_kernel<1><<<dim3(CDIM / 128, UT_MAX), 256, 0, stream>>>(
        mid, wd9, mid2, nullptr, grows, gww, ecnt, tile_map, ntiles, ssc, 0, 0);
    combine_kernel<<<T_TOK, 256, 0, stream>>>(mid2, ntiles, tokpos, tokw, ssc, y);
  } else if (mid_avail >= MIDB) {
    // ATOMIC tier
    hipMemsetAsync(y, 0, (size_t)T_TOK * CDIM * sizeof(float), stream);
    gemm1_pipe_kernel<<<dim3(HDIM / 64, UT_MAX), 256, 0, stream>>>(
        xb, wg9, wu9, mid, grows, ecnt, tile_map, ntiles, 0, 0);
    gemm2_pipe_kernel<0><<<dim3(CDIM / 128, UT_MAX), 256, 0, stream>>>(
        mid, wd9, nullptr, y, grows, gww, ecnt, tile_map, ntiles, ssc, 0, 0);
  } else {
    // CHUNK tier (atomic)
    hipMemsetAsync(y, 0, (size_t)T_TOK * CDIM * sizeof(float), stream);
    int CH = (int)(mid_avail / TILE_B);
    if (CH < 1) CH = 1;
    for (int c0 = 0; c0 < GT_MAX; c0 += CH) {
      const int g = (GT_MAX - c0) < CH ? (GT_MAX - c0) : CH;
      gemm1_pipe_kernel<<<dim3(HDIM / 64, g), 256, 0, stream>>>(
          xb, wg9, wu9, mid, grows, ecnt, tile_map, ntiles, 1, c0);
      gemm2_pipe_kernel<0><<<dim3(CDIM / 128, g), 256, 0, stream>>>(
          mid, wd9, nullptr, y, grows, gww, ecnt, tile_map, ntiles, ssc, 1, c0);
    }
    for (int c0 = 0; c0 < T_TOK / 128; c0 += CH) {
      const int g = (T_TOK / 128 - c0) < CH ? (T_TOK / 128 - c0) : CH;
      gemm1_pipe_kernel<<<dim3(HDIM / 64, g), 256, 0, stream>>>(
          xb, wg9, wu9, mid, grows, ecnt, tile_map, ntiles, 2, c0);
      gemm2_pipe_kernel<0><<<dim3(CDIM / 128, g), 256, 0, stream>>>(
          mid, wd9, nullptr, y, grows, gww, ecnt, tile_map, ntiles, ssc, 2, c0);
    }
  }
}

// Round 10
// 1014.329 us; speedup vs baseline: 1.0287x; 1.0287x over previous
//
#include <hip/hip_runtime.h>
#include <hip/hip_bf16.h>
#include <stdint.h>

#define T_TOK 8192
#define CDIM  1024
#define HDIM  4096
#define NEXP  8
#define TOPK_ 2
#define GT_MAX 72          // grouped 256-row tiles upper bound
#define UT_MAX 104         // grouped + 32 dense tiles
#define GROWS_MAX (GT_MAX * 256)

typedef __attribute__((ext_vector_type(8))) short short8;
typedef __attribute__((ext_vector_type(4))) float f32x4;

__device__ __forceinline__ void gload16(const short* g, short* l) {
  __builtin_amdgcn_global_load_lds(
      (const __attribute__((address_space(1))) unsigned int*)(g),
      (__attribute__((address_space(3))) unsigned int*)(l), 16, 0, 0);
}

// ---------------- gate phase A (+ fused x->bf16) ----------------
__global__ __launch_bounds__(256) void gate_kernel(
    const float* __restrict__ x, const float* __restrict__ gw,
    int* __restrict__ tokinfo, float* __restrict__ tokw,
    int* __restrict__ bcnt, float* __restrict__ spart,
    __hip_bfloat16* __restrict__ xb)
{
  const int wid = threadIdx.x >> 6, lane = threadIdx.x & 63;
  const int t = blockIdx.x * 4 + wid;
  float acc[NEXP];
#pragma unroll
  for (int e = 0; e < NEXP; ++e) acc[e] = 0.f;
  const float4* xr = (const float4*)x + (size_t)t * (CDIM / 4);
  const float4* gw4 = (const float4*)gw;
  uint2* xbo = (uint2*)(xb + (size_t)t * CDIM);
#pragma unroll
  for (int i = 0; i < CDIM / 256; ++i) {
    const float4 xv = xr[lane + 64 * i];
    union { __hip_bfloat16 h[4]; uint2 u; } o;
    o.h[0] = __float2bfloat16(xv.x); o.h[1] = __float2bfloat16(xv.y);
    o.h[2] = __float2bfloat16(xv.z); o.h[3] = __float2bfloat16(xv.w);
    xbo[lane + 64 * i] = o.u;
#pragma unroll
    for (int e = 0; e < NEXP; ++e) {
      const float4 gv = gw4[e * (CDIM / 4) + lane + 64 * i];
      acc[e] += xv.x * gv.x + xv.y * gv.y + xv.z * gv.z + xv.w * gv.w;
    }
  }
#pragma unroll
  for (int off = 32; off > 0; off >>= 1) {
#pragma unroll
    for (int e = 0; e < NEXP; ++e) acc[e] += __shfl_xor(acc[e], off);
  }
  float mx = acc[0];
#pragma unroll
  for (int e = 1; e < NEXP; ++e) mx = fmaxf(mx, acc[e]);
  float p[NEXP]; float s = 0.f;
#pragma unroll
  for (int e = 0; e < NEXP; ++e) { p[e] = __expf(acc[e] - mx); s += p[e]; }
  const float inv = 1.f / s;
#pragma unroll
  for (int e = 0; e < NEXP; ++e) p[e] *= inv;
  float v0 = p[0]; int i0 = 0;
#pragma unroll
  for (int e = 1; e < NEXP; ++e) if (p[e] > v0) { v0 = p[e]; i0 = e; }
  float v1 = -1.f; int i1 = 0;
#pragma unroll
  for (int e = 0; e < NEXP; ++e) if (e != i0 && p[e] > v1) { v1 = p[e]; i1 = e; }

  __shared__ float sp[4][NEXP];
  __shared__ int   se[4][2];
  __shared__ float swt[4][2];
  if (lane == 0) {
#pragma unroll
    for (int e = 0; e < NEXP; ++e) sp[wid][e] = p[e];
    const float wn = 1.f / (v0 + v1);
    se[wid][0] = i0; se[wid][1] = i1;
    swt[wid][0] = v0 * wn; swt[wid][1] = v1 * wn;
  }
  __syncthreads();
  if (threadIdx.x == 0) {
    int cnt[NEXP];
#pragma unroll
    for (int e = 0; e < NEXP; ++e) cnt[e] = 0;
#pragma unroll
    for (int tt = 0; tt < 4; ++tt) {
      const int e0 = se[tt][0], e1 = se[tt][1];
      const int r0 = cnt[e0]++; const int r1 = cnt[e1]++;
      tokinfo[blockIdx.x * 4 + tt] = e0 | (e1 << 3) | (r0 << 6) | (r1 << 10);
      ((float2*)tokw)[blockIdx.x * 4 + tt] = make_float2(swt[tt][0], swt[tt][1]);
    }
#pragma unroll
    for (int e = 0; e < NEXP; ++e) bcnt[blockIdx.x * NEXP + e] = cnt[e];
  }
  if (threadIdx.x < NEXP)
    spart[blockIdx.x * NEXP + threadIdx.x] =
        sp[0][threadIdx.x] + sp[1][threadIdx.x] + sp[2][threadIdx.x] + sp[3][threadIdx.x];
}

// ---------------- gate phase B: scan -> offsets, ecnt, 256-tile map, aux ----------------
__global__ __launch_bounds__(512) void scan_kernel(
    const int* __restrict__ bcnt, int* __restrict__ boff, int* __restrict__ ecnt,
    const float* __restrict__ spart, float* __restrict__ aux_out,
    int* __restrict__ pad_off, int* __restrict__ tile_map, int* __restrict__ ntiles)
{
  const int w = threadIdx.x >> 6, l = threadIdx.x & 63;
  int run = 0;
#pragma unroll 4
  for (int c = 0; c < (T_TOK / 4) / 64; ++c) {
    const int b = c * 64 + l;
    const int v = bcnt[b * NEXP + w];
    int sc = v;
#pragma unroll
    for (int off = 1; off < 64; off <<= 1) {
      const int t = __shfl_up(sc, off);
      if (l >= off) sc += t;
    }
    boff[b * NEXP + w] = run + sc - v;
    run += __shfl(sc, 63);
  }
  if (l == 0) ecnt[w] = run;
  float fs = 0.f;
  for (int c = 0; c < (T_TOK / 4) / 64; ++c) fs += spart[(c * 64 + l) * NEXP + w];
#pragma unroll
  for (int off = 32; off > 0; off >>= 1) fs += __shfl_xor(fs, off);
  __shared__ float pis[NEXP];
  __shared__ int cs[NEXP];
  if (l == 0) { pis[w] = fs; cs[w] = run; }
  __syncthreads();
  if (threadIdx.x == 0) {
    float aux = 0.f;
#pragma unroll
    for (int e = 0; e < NEXP; ++e) {
      const float Pi = pis[e] / (float)T_TOK;
      const float ce = (float)cs[e] / (float)(T_TOK * TOPK_);
      aux += Pi * ce * (float)NEXP;
    }
    aux_out[0] = aux * 0.01f;
    ecnt[8] = T_TOK;  // dense pseudo-expert
    int acc = 0, nt = 0;
    for (int e = 0; e < NEXP; ++e) {
      pad_off[e] = acc;
      const int te = (cs[e] + 255) >> 8;
      for (int t = 0; t < te; ++t) { tile_map[nt] = e | ((t * 256) << 4); ++nt; }
      acc += te * 256;
    }
    ntiles[0] = nt;
    for (int t = 0; t < T_TOK / 256; ++t) { tile_map[nt] = 8 | ((t * 256) << 4); ++nt; }
    ntiles[1] = nt;
  }
}

// ---------------- gate phase C: scatter into 256-padded concat list + tokpos ----------------
__global__ __launch_bounds__(256) void scatter_kernel(
    const int* __restrict__ tokinfo, const float* __restrict__ tokw,
    const int* __restrict__ boff, const int* __restrict__ pad_off,
    int* __restrict__ grows, float* __restrict__ gww, int2* __restrict__ tokpos)
{
  const int t = blockIdx.x * 256 + threadIdx.x;
  const int info = tokinfo[t];
  const int e0 = info & 7, e1 = (info >> 3) & 7;
  const int r0 = (info >> 6) & 15, r1 = (info >> 10) & 15;
  const int b = t >> 2;
  const float2 wv = ((const float2*)tokw)[t];
  const int g0 = pad_off[e0] + boff[b * NEXP + e0] + r0;
  grows[g0] = t; gww[g0] = wv.x;
  const int g1 = pad_off[e1] + boff[b * NEXP + e1] + r1;
  grows[g1] = t; gww[g1] = wv.y;
  tokpos[t] = make_int2(g0, g1);
}

// ---------------- batched transpose+convert ----------------
struct TD { const float* src; __hip_bfloat16* dst; int N; int nsh; int M; };
struct TB { TD d[27]; };
__global__ __launch_bounds__(256) void tbatch_kernel(TB tb)
{
  const int m = blockIdx.x >> 12;
  const int t = blockIdx.x & 4095;
  const TD td = tb.d[m];
  const int n0 = (t & ((1 << td.nsh) - 1)) << 5;
  const int m0 = (t >> td.nsh) << 5;
  __shared__ float tile[32][33];
  const int tx = threadIdx.x & 31, ty = threadIdx.x >> 5;
#pragma unroll
  for (int i = 0; i < 4; ++i)
    tile[ty + 8 * i][tx] = td.src[(size_t)(m0 + ty + 8 * i) * td.N + n0 + tx];
  __syncthreads();
#pragma unroll
  for (int i = 0; i < 4; ++i)
    td.dst[(size_t)(n0 + ty + 8 * i) * td.M + m0 + tx] = __float2bfloat16(tile[tx][ty + 8 * i]);
}

// ---------------- GEMM1: 256x256(GU) tile, BK=64 dbuf, one barrier per K-tile ----------------
__global__ __launch_bounds__(512, 2) void gemm1_pipe_kernel(
    const __hip_bfloat16* __restrict__ Abase,
    const __hip_bfloat16* __restrict__ B0mat, const __hip_bfloat16* __restrict__ B1mat,
    __hip_bfloat16* __restrict__ midout,
    const int* __restrict__ rowlist, const int* __restrict__ ecnt,
    const int* __restrict__ tile_map, const int* __restrict__ ntiles,
    int mode, int tile_base)
{
  constexpr int K = CDIM;
  constexpr int NTL = K / 64;                   // 16 K-tiles
  __shared__ __align__(16) short lds[65536];    // A: 2x16384 @0, B: 2x16384 @32768 (128 KB)

  int ti = blockIdx.y + tile_base;
  if (mode == 2) ti += ntiles[0];
  const int hi = (mode == 1) ? ntiles[0] : ntiles[1];
  if (ti >= hi) return;
  const int tm = tile_map[ti];
  const int e = tm & 15, rb = tm >> 4;
  const int rows_valid = ecnt[e] - rb;
  const int gbmid = (int)blockIdx.y * 256;
  const int glist = ti * 256;

  const int t = threadIdx.x, l = t & 63, w = t >> 6;
  const int wr = w >> 2, wc = w & 3;            // 2M x 4N waves
  const int n0h = blockIdx.x * 128;             // h-col base

  // staging: thread covers tile-rows rbase + {0,64,128,192}, swizzled k-chunk
  const int rbase = w * 8 + (l >> 3);
  const int ksrc = ((l & 7) ^ ((l >> 3) & 7)) * 8;
  const short* pA[4]; const short* pB[4];
#pragma unroll
  for (int j = 0; j < 4; ++j) {
    const int rl_ = j * 64 + rbase;
    int rg;
    if (e == 8) rg = rb + rl_;
    else { const int c = rl_ < rows_valid ? rl_ : rows_valid - 1; rg = rowlist[glist + c]; }
    pA[j] = (const short*)Abase + (size_t)rg * K + ksrc;
    const int s = (rl_ >> 4) & 1;
    const int h = n0h + (rl_ >> 5) * 16 + (rl_ & 15);
    pB[j] = (const short*)(s ? B1mat : B0mat) + (size_t)e * CDIM * HDIM + (size_t)h * K + ksrc;
  }
  const int dst0 = w * 512 + l * 8;

#define STG(tt) { const int bb_ = ((tt) & 1) * 16384; \
    gload16(pA[0] + (tt) * 64, lds + bb_ + dst0);          gload16(pB[0] + (tt) * 64, lds + 32768 + bb_ + dst0); \
    gload16(pA[1] + (tt) * 64, lds + bb_ + 4096 + dst0);   gload16(pB[1] + (tt) * 64, lds + 32768 + bb_ + 4096 + dst0); \
    gload16(pA[2] + (tt) * 64, lds + bb_ + 8192 + dst0);   gload16(pB[2] + (tt) * 64, lds + 32768 + bb_ + 8192 + dst0); \
    gload16(pA[3] + (tt) * 64, lds + bb_ + 12288 + dst0);  gload16(pB[3] + (tt) * 64, lds + 32768 + bb_ + 12288 + dst0); }

  f32x4 acc[8][4];
#pragma unroll
  for (int i = 0; i < 8; ++i)
#pragma unroll
    for (int j = 0; j < 4; ++j) acc[i][j] = (f32x4){0.f, 0.f, 0.f, 0.f};

  STG(0)
  for (int tt = 0; tt < NTL; ++tt) {
    // tile tt landed (own 8 loads) + all waves arrived; prior buf reads retired.
    asm volatile("s_waitcnt vmcnt(0)\n\ts_barrier" ::: "memory");
    __builtin_amdgcn_sched_barrier(0);
    if (tt + 1 < NTL) STG(tt + 1)
    const int ab = (tt & 1) * 16384, bb = 32768 + (tt & 1) * 16384;
#pragma unroll
    for (int ks = 0; ks < 2; ++ks) {
      short8 af[8], bf[4];
      const int cb = ks * 4 + (l >> 4);
      const int csw = (cb ^ (l & 7)) * 8;
#pragma unroll
      for (int mi = 0; mi < 8; ++mi)
        af[mi] = *(const short8*)(lds + ab + (wr * 128 + mi * 16 + (l & 15)) * 64 + csw);
#pragma unroll
      for (int ni = 0; ni < 4; ++ni)
        bf[ni] = *(const short8*)(lds + bb + (wc * 64 + ni * 16 + (l & 15)) * 64 + csw);
      __builtin_amdgcn_s_setprio(1);
#pragma unroll
      for (int mi = 0; mi < 8; ++mi)
#pragma unroll
        for (int ni = 0; ni < 4; ++ni)
          acc[mi][ni] = __builtin_amdgcn_mfma_f32_16x16x32_bf16(af[mi], bf[ni], acc[mi][ni], 0, 0, 0);
      __builtin_amdgcn_s_setprio(0);
    }
  }
#undef STG

  const int rl = (l >> 4) * 4, cl = l & 15;
#pragma unroll
  for (int mi = 0; mi < 8; ++mi) {
#pragma unroll
    for (int j = 0; j < 4; ++j) {
      const int rlocal = wr * 128 + mi * 16 + rl + j;
      if (rlocal < rows_valid) {
        __hip_bfloat16* mp = midout + (size_t)(gbmid + rlocal) * HDIM;
#pragma unroll
        for (int jj = 0; jj < 2; ++jj) {
          const float g = acc[mi][jj * 2][j], u = acc[mi][jj * 2 + 1][j];
          const float sv = g / (1.f + __expf(-g));
          mp[n0h + (wc * 2 + jj) * 16 + cl] = __float2bfloat16(sv * u);
        }
      }
    }
  }
}

// ---------------- GEMM2: 256x128 tile, BK=64 dbuf, one barrier per K-tile ----------------
template <int OST>
__global__ __launch_bounds__(512, 2) void gemm2_pipe_kernel(
    const __hip_bfloat16* __restrict__ mid, const __hip_bfloat16* __restrict__ wd9,
    float* __restrict__ mid2, float* __restrict__ y,
    const int* __restrict__ rowlist, const float* __restrict__ roww,
    const int* __restrict__ ecnt, const int* __restrict__ tile_map,
    const int* __restrict__ ntiles, const float* __restrict__ ssc,
    int mode, int tile_base)
{
  constexpr int K = HDIM;
  constexpr int NTL = K / 64;                   // 64 K-tiles
  __shared__ __align__(16) short lds[49152];    // A: 2x16384 @0, B: 2x8192 @32768 (96 KB)

  int ti = blockIdx.y + tile_base;
  if (mode == 2) ti += ntiles[0];
  const int hi = (mode == 1) ? ntiles[0] : ntiles[1];
  if (ti >= hi) return;
  const int tm = tile_map[ti];
  const int e = tm & 15, rb = tm >> 4;
  const int rows_valid = ecnt[e] - rb;
  const int gbmid = (int)blockIdx.y * 256;
  const int glist = ti * 256;

  const int t = threadIdx.x, l = t & 63, w = t >> 6;
  const int wr = w & 3, wc = w >> 2;            // 4M x 2N waves (64x64 per wave)
  const int n0 = blockIdx.x * 128;

  const int rbase = w * 8 + (l >> 3);
  const int ksrc = ((l & 7) ^ ((l >> 3) & 7)) * 8;
  const short* pA[4]; const short* pB[2];
#pragma unroll
  for (int j = 0; j < 4; ++j)
    pA[j] = (const short*)mid + (size_t)(gbmid + j * 64 + rbase) * K + ksrc;
#pragma unroll
  for (int j = 0; j < 2; ++j)
    pB[j] = (const short*)wd9 + (size_t)e * CDIM * HDIM + (size_t)(n0 + j * 64 + rbase) * K + ksrc;
  const int dst0 = w * 512 + l * 8;

#define STG2(tt) { const int ab_ = ((tt) & 1) * 16384, bb_ = 32768 + ((tt) & 1) * 8192; \
    gload16(pA[0] + (size_t)(tt) * 64, lds + ab_ + dst0); \
    gload16(pA[1] + (size_t)(tt) * 64, lds + ab_ + 4096 + dst0); \
    gload16(pA[2] + (size_t)(tt) * 64, lds + ab_ + 8192 + dst0); \
    gload16(pA[3] + (size_t)(tt) * 64, lds + ab_ + 12288 + dst0); \
    gload16(pB[0] + (size_t)(tt) * 64, lds + bb_ + dst0); \
    gload16(pB[1] + (size_t)(tt) * 64, lds + bb_ + 4096 + dst0); }

  f32x4 acc[4][4];
#pragma unroll
  for (int i = 0; i < 4; ++i)
#pragma unroll
    for (int j = 0; j < 4; ++j) acc[i][j] = (f32x4){0.f, 0.f, 0.f, 0.f};

  STG2(0)
  for (int tt = 0; tt < NTL; ++tt) {
    asm volatile("s_waitcnt vmcnt(0)\n\ts_barrier" ::: "memory");
    __builtin_amdgcn_sched_barrier(0);
    if (tt + 1 < NTL) STG2(tt + 1)
    const int ab = (tt & 1) * 16384, bb = 32768 + (tt & 1) * 8192;
#pragma unroll
    for (int ks = 0; ks < 2; ++ks) {
      short8 af[4], bf[4];
      const int cb = ks * 4 + (l >> 4);
      const int csw = (cb ^ (l & 7)) * 8;
#pragma unroll
      for (int mi = 0; mi < 4; ++mi)
        af[mi] = *(const short8*)(lds + ab + (wr * 64 + mi * 16 + (l & 15)) * 64 + csw);
#pragma unroll
      for (int ni = 0; ni < 4; ++ni)
        bf[ni] = *(const short8*)(lds + bb + (wc * 64 + ni * 16 + (l & 15)) * 64 + csw);
      __builtin_amdgcn_s_setprio(1);
#pragma unroll
      for (int mi = 0; mi < 4; ++mi)
#pragma unroll
        for (int ni = 0; ni < 4; ++ni)
          acc[mi][ni] = __builtin_amdgcn_mfma_f32_16x16x32_bf16(af[mi], bf[ni], acc[mi][ni], 0, 0, 0);
      __builtin_amdgcn_s_setprio(0);
    }
  }
#undef STG2

  const int rl = (l >> 4) * 4, cl = l & 15;
  if (OST) {
#pragma unroll
    for (int mi = 0; mi < 4; ++mi) {
#pragma unroll
      for (int j = 0; j < 4; ++j) {
        const int rlocal = wr * 64 + mi * 16 + rl + j;
        if (rlocal < rows_valid) {
          float* mp = mid2 + (size_t)(glist + rlocal) * CDIM + n0 + wc * 64 + cl;
#pragma unroll
          for (int ni = 0; ni < 4; ++ni) mp[ni * 16] = acc[mi][ni][j];
        }
      }
    }
  } else {
    const float ss = ssc[0];
#pragma unroll
    for (int mi = 0; mi < 4; ++mi) {
#pragma unroll
      for (int j = 0; j < 4; ++j) {
        const int rlocal = wr * 64 + mi * 16 + rl + j;
        if (rlocal < rows_valid) {
          int tok; float wgt;
          if (e == 8) { tok = rb + rlocal; wgt = ss; }
          else { tok = rowlist[glist + rlocal]; wgt = roww[glist + rlocal]; }
          float* yp = y + (size_t)tok * CDIM + n0 + wc * 64 + cl;
#pragma unroll
          for (int ni = 0; ni < 4; ++ni)
            unsafeAtomicAdd(yp + ni * 16, wgt * acc[mi][ni][j]);
        }
      }
    }
  }
}

// ---------------- combine: y[t] = ss*dense + w0*exp0 + w1*exp1 ----------------
__global__ __launch_bounds__(256) void combine_kernel(
    const float* __restrict__ mid2, const int* __restrict__ ntiles,
    const int2* __restrict__ tokpos, const float* __restrict__ tokw,
    const float* __restrict__ ssc, float* __restrict__ y)
{
  const int t = blockIdx.x;
  const int c = threadIdx.x * 4;
  const int dbase = ntiles[0] * 256;
  const int2 gp = tokpos[t];
  const float2 wv = ((const float2*)tokw)[t];
  const float ss = ssc[0];
  const float4 d = *(const float4*)(mid2 + (size_t)(dbase + t) * CDIM + c);
  const float4 a = *(const float4*)(mid2 + (size_t)gp.x * CDIM + c);
  const float4 b = *(const float4*)(mid2 + (size_t)gp.y * CDIM + c);
  float4 r;
  r.x = ss * d.x + wv.x * a.x + wv.y * b.x;
  r.y = ss * d.y + wv.x * a.y + wv.y * b.y;
  r.z = ss * d.z + wv.x * a.z + wv.y * b.z;
  r.w = ss * d.w + wv.x * a.w + wv.y * b.w;
  *(float4*)(y + (size_t)t * CDIM + c) = r;
}

// ---------------- host ----------------
extern "C" void kernel_launch(void* const* d_in, const int* in_sizes, int n_in,
                              void* d_out, int out_size, void* d_ws, size_t ws_size,
                              hipStream_t stream)
{
  const float* x   = (const float*)d_in[0];
  const float* gw  = (const float*)d_in[1];
  const float* wg  = (const float*)d_in[2];
  const float* wu  = (const float*)d_in[3];
  const float* wd  = (const float*)d_in[4];
  const float* swg = (const float*)d_in[5];
  const float* swu = (const float*)d_in[6];
  const float* swd = (const float*)d_in[7];
  const float* ssc = (const float*)d_in[8];
  float* y = (float*)d_out;

  auto al = [](size_t v) { return (v + 255) & ~(size_t)255; };
  char* ws = (char*)d_ws;
  size_t off = 0;
  __hip_bfloat16* xb = (__hip_bfloat16*)(ws + off); off += al((size_t)T_TOK * CDIM * 2);
  int*   tokinfo = (int*)(ws + off);   off += al((size_t)T_TOK * 4);
  float* tokw    = (float*)(ws + off); off += al((size_t)T_TOK * 8);
  int2*  tokpos  = (int2*)(ws + off);  off += al((size_t)T_TOK * 8);
  int*   bcnt    = (int*)(ws + off);   off += al((size_t)(T_TOK / 4) * NEXP * 4);
  int*   boffb   = (int*)(ws + off);   off += al((size_t)(T_TOK / 4) * NEXP * 4);
  float* spart   = (float*)(ws + off); off += al((size_t)(T_TOK / 4) * NEXP * 4);
  int*   ecnt    = (int*)(ws + off);   off += 256;   // 9 used
  int*   pad_off = (int*)(ws + off);   off += 256;
  int*   ntiles  = (int*)(ws + off);   off += 256;
  int*   tile_map= (int*)(ws + off);   off += al((size_t)UT_MAX * 4);
  int*   grows   = (int*)(ws + off);   off += al((size_t)GROWS_MAX * 4);
  float* gww     = (float*)(ws + off); off += al((size_t)GROWS_MAX * 4);

  const size_t WMAT = (size_t)CDIM * HDIM;
  __hip_bfloat16* wg9 = (__hip_bfloat16*)(ws + off); off += 9 * WMAT * 2;
  __hip_bfloat16* wu9 = (__hip_bfloat16*)(ws + off); off += 9 * WMAT * 2;
  __hip_bfloat16* wd9 = (__hip_bfloat16*)(ws + off); off += 9 * WMAT * 2;
  __hip_bfloat16* mid = (__hip_bfloat16*)(ws + off);
  const size_t mid_avail = (ws_size > off) ? (ws_size - off) : 0;
  const size_t TILE_B = (size_t)256 * HDIM * 2;                 // 2 MB per 256-row mid tile
  const size_t MIDB   = (size_t)UT_MAX * TILE_B;                // bf16 mid (full)
  const size_t MID2B  = (size_t)UT_MAX * 256 * CDIM * 4;        // fp32 partials

  gate_kernel<<<T_TOK / 4, 256, 0, stream>>>(x, gw, tokinfo, tokw, bcnt, spart, xb);
  scan_kernel<<<1, 512, 0, stream>>>(bcnt, boffb, ecnt, spart, y + (size_t)T_TOK * CDIM,
                                     pad_off, tile_map, ntiles);
  scatter_kernel<<<T_TOK / 256, 256, 0, stream>>>(tokinfo, tokw, boffb, pad_off,
                                                  grows, gww, tokpos);

  TB tb;
  for (int e = 0; e < 8; ++e) {
    tb.d[e]      = TD{wg + e * WMAT, wg9 + e * WMAT, HDIM, 7, CDIM};
    tb.d[8 + e]  = TD{wu + e * WMAT, wu9 + e * WMAT, HDIM, 7, CDIM};
    tb.d[16 + e] = TD{wd + e * WMAT, wd9 + e * WMAT, CDIM, 5, HDIM};
  }
  tb.d[24] = TD{swg, wg9 + 8 * WMAT, HDIM, 7, CDIM};
  tb.d[25] = TD{swu, wu9 + 8 * WMAT, HDIM, 7, CDIM};
  tb.d[26] = TD{swd, wd9 + 8 * WMAT, CDIM, 5, HDIM};
  tbatch_kernel<<<27 * 4096, 256, 0, stream>>>(tb);

  if (mid_avail >= MIDB + MID2B) {
    // STORE tier: unified gemm1, gemm2 plain stores, combine (no atomics anywhere)
    float* mid2 = (float*)((char*)mid + MIDB);
    gemm1_pipe_kernel<<<dim3(HDIM / 128, UT_MAX), 512, 0, stream>>>(
        xb, wg9, wu9, mid, grows, ecnt, tile_map, ntiles, 0, 0);
    gemm2_pipe_kernel<1><<<dim3(CDIM / 128, UT_MAX), 512, 0, stream>>>(
        mid, wd9, mid2, nullptr, grows, gww, ecnt, tile_map, ntiles, ssc, 0, 0);
    combine_kernel<<<T_TOK, 256, 0, stream>>>(mid2, ntiles, tokpos, tokw, ssc, y);
  } else if (mid_avail >= MIDB) {
    // ATOMIC tier
    hipMemsetAsync(y, 0, (size_t)T_TOK * CDIM * sizeof(float), stream);
    gemm1_pipe_kernel<<<dim3(HDIM / 128, UT_MAX), 512, 0, stream>>>(
        xb, wg9, wu9, mid, grows, ecnt, tile_map, ntiles, 0, 0);
    gemm2_pipe_kernel<0><<<dim3(CDIM / 128, UT_MAX), 512, 0, stream>>>(
        mid, wd9, nullptr, y, grows, gww, ecnt, tile_map, ntiles, ssc, 0, 0);
  } else {
    // CHUNK tier (atomic)
    hipMemsetAsync(y, 0, (size_t)T_TOK * CDIM * sizeof(float), stream);
    int CH = (int)(mid_avail / TILE_B);
    if (CH < 1) CH = 1;
    for (int c0 = 0; c0 < GT_MAX; c0 += CH) {
      const int g = (GT_MAX - c0) < CH ? (GT_MAX - c0) : CH;
      gemm1_pipe_kernel<<<dim3(HDIM / 128, g), 512, 0, stream>>>(
          xb, wg9, wu9, mid, grows, ecnt, tile_map, ntiles, 1, c0);
      gemm2_pipe_kernel<0><<<dim3(CDIM / 128, g), 512, 0, stream>>>(
          mid, wd9, nullptr, y, grows, gww, ecnt, tile_map, ntiles, ssc, 1, c0);
    }
    for (int c0 = 0; c0 < 32; c0 += CH) {
      const int g = (32 - c0) < CH ? (32 - c0) : CH;
      gemm1_pipe_kernel<<<dim3(HDIM / 128, g), 512, 0, stream>>>(
          xb, wg9, wu9, mid, grows, ecnt, tile_map, ntiles, 2, c0);
      gemm2_pipe_kernel<0><<<dim3(CDIM / 128, g), 512, 0, stream>>>(
          mid, wd9, nullptr, y, grows, gww, ecnt, tile_map, ntiles, ssc, 2, c0);
    }
  }
}

// Round 11
// 972.309 us; speedup vs baseline: 1.0731x; 1.0432x over previous
//
#include <hip/hip_runtime.h>
#include <hip/hip_bf16.h>
#include <stdint.h>

#define T_TOK 8192
#define CDIM  1024
#define HDIM  4096
#define NEXP  8
#define TOPK_ 2
#define GT_MAX 72          // grouped 256-row tiles upper bound
#define UT_MAX 104         // grouped + 32 dense tiles
#define GROWS_MAX (GT_MAX * 256)

typedef __attribute__((ext_vector_type(8))) short short8;
typedef __attribute__((ext_vector_type(4))) float f32x4;

__device__ __forceinline__ void gload16(const short* g, short* l) {
  __builtin_amdgcn_global_load_lds(
      (const __attribute__((address_space(1))) unsigned int*)(g),
      (__attribute__((address_space(3))) unsigned int*)(l), 16, 0, 0);
}

#define BAR       asm volatile("s_barrier" ::: "memory")
#define LGKM0     do { asm volatile("s_waitcnt lgkmcnt(0)" ::: "memory"); \
                       __builtin_amdgcn_sched_barrier(0); } while (0)

// ---------------- gate phase A (+ fused x->bf16) ----------------
__global__ __launch_bounds__(256) void gate_kernel(
    const float* __restrict__ x, const float* __restrict__ gw,
    int* __restrict__ tokinfo, float* __restrict__ tokw,
    int* __restrict__ bcnt, float* __restrict__ spart,
    __hip_bfloat16* __restrict__ xb)
{
  const int wid = threadIdx.x >> 6, lane = threadIdx.x & 63;
  const int t = blockIdx.x * 4 + wid;
  float acc[NEXP];
#pragma unroll
  for (int e = 0; e < NEXP; ++e) acc[e] = 0.f;
  const float4* xr = (const float4*)x + (size_t)t * (CDIM / 4);
  const float4* gw4 = (const float4*)gw;
  uint2* xbo = (uint2*)(xb + (size_t)t * CDIM);
#pragma unroll
  for (int i = 0; i < CDIM / 256; ++i) {
    const float4 xv = xr[lane + 64 * i];
    union { __hip_bfloat16 h[4]; uint2 u; } o;
    o.h[0] = __float2bfloat16(xv.x); o.h[1] = __float2bfloat16(xv.y);
    o.h[2] = __float2bfloat16(xv.z); o.h[3] = __float2bfloat16(xv.w);
    xbo[lane + 64 * i] = o.u;
#pragma unroll
    for (int e = 0; e < NEXP; ++e) {
      const float4 gv = gw4[e * (CDIM / 4) + lane + 64 * i];
      acc[e] += xv.x * gv.x + xv.y * gv.y + xv.z * gv.z + xv.w * gv.w;
    }
  }
#pragma unroll
  for (int off = 32; off > 0; off >>= 1) {
#pragma unroll
    for (int e = 0; e < NEXP; ++e) acc[e] += __shfl_xor(acc[e], off);
  }
  float mx = acc[0];
#pragma unroll
  for (int e = 1; e < NEXP; ++e) mx = fmaxf(mx, acc[e]);
  float p[NEXP]; float s = 0.f;
#pragma unroll
  for (int e = 0; e < NEXP; ++e) { p[e] = __expf(acc[e] - mx); s += p[e]; }
  const float inv = 1.f / s;
#pragma unroll
  for (int e = 0; e < NEXP; ++e) p[e] *= inv;
  float v0 = p[0]; int i0 = 0;
#pragma unroll
  for (int e = 1; e < NEXP; ++e) if (p[e] > v0) { v0 = p[e]; i0 = e; }
  float v1 = -1.f; int i1 = 0;
#pragma unroll
  for (int e = 0; e < NEXP; ++e) if (e != i0 && p[e] > v1) { v1 = p[e]; i1 = e; }

  __shared__ float sp[4][NEXP];
  __shared__ int   se[4][2];
  __shared__ float swt[4][2];
  if (lane == 0) {
#pragma unroll
    for (int e = 0; e < NEXP; ++e) sp[wid][e] = p[e];
    const float wn = 1.f / (v0 + v1);
    se[wid][0] = i0; se[wid][1] = i1;
    swt[wid][0] = v0 * wn; swt[wid][1] = v1 * wn;
  }
  __syncthreads();
  if (threadIdx.x == 0) {
    int cnt[NEXP];
#pragma unroll
    for (int e = 0; e < NEXP; ++e) cnt[e] = 0;
#pragma unroll
    for (int tt = 0; tt < 4; ++tt) {
      const int e0 = se[tt][0], e1 = se[tt][1];
      const int r0 = cnt[e0]++; const int r1 = cnt[e1]++;
      tokinfo[blockIdx.x * 4 + tt] = e0 | (e1 << 3) | (r0 << 6) | (r1 << 10);
      ((float2*)tokw)[blockIdx.x * 4 + tt] = make_float2(swt[tt][0], swt[tt][1]);
    }
#pragma unroll
    for (int e = 0; e < NEXP; ++e) bcnt[blockIdx.x * NEXP + e] = cnt[e];
  }
  if (threadIdx.x < NEXP)
    spart[blockIdx.x * NEXP + threadIdx.x] =
        sp[0][threadIdx.x] + sp[1][threadIdx.x] + sp[2][threadIdx.x] + sp[3][threadIdx.x];
}

// ---------------- gate phase B: scan -> offsets, ecnt, 256-tile map, aux ----------------
__global__ __launch_bounds__(512) void scan_kernel(
    const int* __restrict__ bcnt, int* __restrict__ boff, int* __restrict__ ecnt,
    const float* __restrict__ spart, float* __restrict__ aux_out,
    int* __restrict__ pad_off, int* __restrict__ tile_map, int* __restrict__ ntiles)
{
  const int w = threadIdx.x >> 6, l = threadIdx.x & 63;
  int run = 0;
#pragma unroll 4
  for (int c = 0; c < (T_TOK / 4) / 64; ++c) {
    const int b = c * 64 + l;
    const int v = bcnt[b * NEXP + w];
    int sc = v;
#pragma unroll
    for (int off = 1; off < 64; off <<= 1) {
      const int t = __shfl_up(sc, off);
      if (l >= off) sc += t;
    }
    boff[b * NEXP + w] = run + sc - v;
    run += __shfl(sc, 63);
  }
  if (l == 0) ecnt[w] = run;
  float fs = 0.f;
  for (int c = 0; c < (T_TOK / 4) / 64; ++c) fs += spart[(c * 64 + l) * NEXP + w];
#pragma unroll
  for (int off = 32; off > 0; off >>= 1) fs += __shfl_xor(fs, off);
  __shared__ float pis[NEXP];
  __shared__ int cs[NEXP];
  if (l == 0) { pis[w] = fs; cs[w] = run; }
  __syncthreads();
  if (threadIdx.x == 0) {
    float aux = 0.f;
#pragma unroll
    for (int e = 0; e < NEXP; ++e) {
      const float Pi = pis[e] / (float)T_TOK;
      const float ce = (float)cs[e] / (float)(T_TOK * TOPK_);
      aux += Pi * ce * (float)NEXP;
    }
    aux_out[0] = aux * 0.01f;
    ecnt[8] = T_TOK;  // dense pseudo-expert
    int acc = 0, nt = 0;
    for (int e = 0; e < NEXP; ++e) {
      pad_off[e] = acc;
      const int te = (cs[e] + 255) >> 8;
      for (int t = 0; t < te; ++t) { tile_map[nt] = e | ((t * 256) << 4); ++nt; }
      acc += te * 256;
    }
    ntiles[0] = nt;
    for (int t = 0; t < T_TOK / 256; ++t) { tile_map[nt] = 8 | ((t * 256) << 4); ++nt; }
    ntiles[1] = nt;
  }
}

// ---------------- gate phase C ----------------
__global__ __launch_bounds__(256) void scatter_kernel(
    const int* __restrict__ tokinfo, const float* __restrict__ tokw,
    const int* __restrict__ boff, const int* __restrict__ pad_off,
    int* __restrict__ grows, float* __restrict__ gww, int2* __restrict__ tokpos)
{
  const int t = blockIdx.x * 256 + threadIdx.x;
  const int info = tokinfo[t];
  const int e0 = info & 7, e1 = (info >> 3) & 7;
  const int r0 = (info >> 6) & 15, r1 = (info >> 10) & 15;
  const int b = t >> 2;
  const float2 wv = ((const float2*)tokw)[t];
  const int g0 = pad_off[e0] + boff[b * NEXP + e0] + r0;
  grows[g0] = t; gww[g0] = wv.x;
  const int g1 = pad_off[e1] + boff[b * NEXP + e1] + r1;
  grows[g1] = t; gww[g1] = wv.y;
  tokpos[t] = make_int2(g0, g1);
}

// ---------------- batched transpose+convert ----------------
struct TD { const float* src; __hip_bfloat16* dst; int N; int nsh; int M; };
struct TB { TD d[27]; };
__global__ __launch_bounds__(256) void tbatch_kernel(TB tb)
{
  const int m = blockIdx.x >> 12;
  const int t = blockIdx.x & 4095;
  const TD td = tb.d[m];
  const int n0 = (t & ((1 << td.nsh) - 1)) << 5;
  const int m0 = (t >> td.nsh) << 5;
  __shared__ float tile[32][33];
  const int tx = threadIdx.x & 31, ty = threadIdx.x >> 5;
#pragma unroll
  for (int i = 0; i < 4; ++i)
    tile[ty + 8 * i][tx] = td.src[(size_t)(m0 + ty + 8 * i) * td.N + n0 + tx];
  __syncthreads();
#pragma unroll
  for (int i = 0; i < 4; ++i)
    td.dst[(size_t)(n0 + ty + 8 * i) * td.M + m0 + tx] = __float2bfloat16(tile[tx][ty + 8 * i]);
}

// ================= GEMM1: 256x256(GU), BK=64, 8-phase interleave, counted vmcnt ============
__global__ __launch_bounds__(512, 1) void gemm1_pipe_kernel(
    const __hip_bfloat16* __restrict__ Abase,
    const __hip_bfloat16* __restrict__ B0mat, const __hip_bfloat16* __restrict__ B1mat,
    __hip_bfloat16* __restrict__ midout,
    const int* __restrict__ rowlist, const int* __restrict__ ecnt,
    const int* __restrict__ tile_map, const int* __restrict__ ntiles,
    int mode, int tile_base)
{
  constexpr int K = CDIM;
  constexpr int NTL = K / 64;                   // 16 K-tiles
  __shared__ __align__(16) short lds[65536];    // A: 2buf x 16384 @0, B: @32768 (128 KB)

  int ti = blockIdx.y + tile_base;
  if (mode == 2) ti += ntiles[0];
  const int hi = (mode == 1) ? ntiles[0] : ntiles[1];
  if (ti >= hi) return;
  const int tm = tile_map[ti];
  const int e = tm & 15, rb = tm >> 4;
  const int rows_valid = ecnt[e] - rb;
  const int gbmid = (int)blockIdx.y * 256;
  const int glist = ti * 256;

  const int t = threadIdx.x, l = t & 63, w = t >> 6;
  const int wr = w >> 2, wc = w & 3;            // 2M x 4N waves, 128x64 out per wave
  const int n0h = blockIdx.x * 128;             // h-col base

  // staging (R10 layout, verified 0 bank conflicts)
  const int rbase = w * 8 + (l >> 3);
  const int ksrc = ((l & 7) ^ ((l >> 3) & 7)) * 8;
  const short* pA[4]; const short* pB[4];
#pragma unroll
  for (int j = 0; j < 4; ++j) {
    const int rl_ = j * 64 + rbase;
    int rg;
    if (e == 8) rg = rb + rl_;
    else { const int c = rl_ < rows_valid ? rl_ : rows_valid - 1; rg = rowlist[glist + c]; }
    pA[j] = (const short*)Abase + (size_t)rg * K + ksrc;
    const int s = (rl_ >> 4) & 1;
    const int h = n0h + (rl_ >> 5) * 16 + (rl_ & 15);
    pB[j] = (const short*)(s ? B1mat : B0mat) + (size_t)e * CDIM * HDIM + (size_t)h * K + ksrc;
  }
  const int dst0 = w * 512 + l * 8;

#define STG_AH(tt, h) { const int b_ = ((tt) & 1) * 16384; \
    gload16(pA[2*(h)]   + (tt) * 64, lds + b_ + (2*(h)) * 4096   + dst0); \
    gload16(pA[2*(h)+1] + (tt) * 64, lds + b_ + (2*(h)+1) * 4096 + dst0); }
#define STG_BH(tt, h) { const int b_ = 32768 + ((tt) & 1) * 16384; \
    gload16(pB[2*(h)]   + (tt) * 64, lds + b_ + (2*(h)) * 4096   + dst0); \
    gload16(pB[2*(h)+1] + (tt) * 64, lds + b_ + (2*(h)+1) * 4096 + dst0); }

  // read bases
  const int l15 = l & 15;
  const int cs0 = (((l >> 4)) ^ (l & 7)) * 8;
  const int cs1 = ((4 + (l >> 4)) ^ (l & 7)) * 8;
  const int afb = (wr * 128 + l15) * 64;
  const int bfb = (wc * 64 + l15) * 64;

  f32x4 acc[8][4];
#pragma unroll
  for (int i = 0; i < 8; ++i)
#pragma unroll
    for (int j = 0; j < 4; ++j) acc[i][j] = (f32x4){0.f, 0.f, 0.f, 0.f};

  short8 af[4][2], bf[4][2];

  // prologue: stage tile 0 fully (8 loads)
  STG_AH(0, 0) STG_AH(0, 1) STG_BH(0, 0) STG_BH(0, 1)

  for (int tt = 0; tt < NTL; ++tt) {
    const int ab = (tt & 1) * 16384, bb = 32768 + (tt & 1) * 16384;
    // ---- boundary: stage next A-half0, counted wait for tile tt's 8 loads ----
    if (tt + 1 < NTL) {
      STG_AH(tt + 1, 0)
      asm volatile("s_waitcnt vmcnt(2)\n\ts_barrier" ::: "memory");
    } else {
      asm volatile("s_waitcnt vmcnt(0)\n\ts_barrier" ::: "memory");
    }
    __builtin_amdgcn_sched_barrier(0);
    // ---- phase A: Q(mi0-3, ni0-1) ----
#pragma unroll
    for (int mi = 0; mi < 4; ++mi) {
      af[mi][0] = *(const short8*)(lds + ab + afb + mi * 1024 + cs0);
      af[mi][1] = *(const short8*)(lds + ab + afb + mi * 1024 + cs1);
    }
#pragma unroll
    for (int ni = 0; ni < 2; ++ni) {
      bf[ni][0] = *(const short8*)(lds + bb + bfb + ni * 1024 + cs0);
      bf[ni][1] = *(const short8*)(lds + bb + bfb + ni * 1024 + cs1);
    }
    if (tt + 1 < NTL) STG_AH(tt + 1, 1)
    BAR; LGKM0;
    __builtin_amdgcn_s_setprio(1);
#pragma unroll
    for (int ks = 0; ks < 2; ++ks)
#pragma unroll
      for (int mi = 0; mi < 4; ++mi)
#pragma unroll
        for (int ni = 0; ni < 2; ++ni)
          acc[mi][ni] = __builtin_amdgcn_mfma_f32_16x16x32_bf16(af[mi][ks], bf[ni][ks], acc[mi][ni], 0, 0, 0);
    __builtin_amdgcn_s_setprio(0);
    BAR;
    // ---- phase B: Q(mi0-3, ni2-3) ----
#pragma unroll
    for (int ni = 2; ni < 4; ++ni) {
      bf[ni][0] = *(const short8*)(lds + bb + bfb + ni * 1024 + cs0);
      bf[ni][1] = *(const short8*)(lds + bb + bfb + ni * 1024 + cs1);
    }
    if (tt + 1 < NTL) STG_BH(tt + 1, 0)
    BAR; LGKM0;
    __builtin_amdgcn_s_setprio(1);
#pragma unroll
    for (int ks = 0; ks < 2; ++ks)
#pragma unroll
      for (int mi = 0; mi < 4; ++mi)
#pragma unroll
        for (int ni = 0; ni < 2; ++ni)
          acc[mi][2 + ni] = __builtin_amdgcn_mfma_f32_16x16x32_bf16(af[mi][ks], bf[2 + ni][ks], acc[mi][2 + ni], 0, 0, 0);
    __builtin_amdgcn_s_setprio(0);
    BAR;
    // ---- phase C: Q(mi4-7, ni0-1) ----
#pragma unroll
    for (int mi = 0; mi < 4; ++mi) {
      af[mi][0] = *(const short8*)(lds + ab + afb + 4096 + mi * 1024 + cs0);
      af[mi][1] = *(const short8*)(lds + ab + afb + 4096 + mi * 1024 + cs1);
    }
    if (tt + 1 < NTL) STG_BH(tt + 1, 1)
    BAR; LGKM0;
    __builtin_amdgcn_s_setprio(1);
#pragma unroll
    for (int ks = 0; ks < 2; ++ks)
#pragma unroll
      for (int mi = 0; mi < 4; ++mi)
#pragma unroll
        for (int ni = 0; ni < 2; ++ni)
          acc[4 + mi][ni] = __builtin_amdgcn_mfma_f32_16x16x32_bf16(af[mi][ks], bf[ni][ks], acc[4 + mi][ni], 0, 0, 0);
    __builtin_amdgcn_s_setprio(0);
    BAR;
    // ---- phase D: Q(mi4-7, ni2-3) (register-only) ----
    __builtin_amdgcn_s_setprio(1);
#pragma unroll
    for (int ks = 0; ks < 2; ++ks)
#pragma unroll
      for (int mi = 0; mi < 4; ++mi)
#pragma unroll
        for (int ni = 0; ni < 2; ++ni)
          acc[4 + mi][2 + ni] = __builtin_amdgcn_mfma_f32_16x16x32_bf16(af[mi][ks], bf[2 + ni][ks], acc[4 + mi][2 + ni], 0, 0, 0);
    __builtin_amdgcn_s_setprio(0);
  }
#undef STG_AH
#undef STG_BH

  const int rl = (l >> 4) * 4, cl = l & 15;
#pragma unroll
  for (int mi = 0; mi < 8; ++mi) {
#pragma unroll
    for (int j = 0; j < 4; ++j) {
      const int rlocal = wr * 128 + mi * 16 + rl + j;
      if (rlocal < rows_valid) {
        __hip_bfloat16* mp = midout + (size_t)(gbmid + rlocal) * HDIM;
#pragma unroll
        for (int jj = 0; jj < 2; ++jj) {
          const float g = acc[mi][jj * 2][j], u = acc[mi][jj * 2 + 1][j];
          const float sv = g / (1.f + __expf(-g));
          mp[n0h + (wc * 2 + jj) * 16 + cl] = __float2bfloat16(sv * u);
        }
      }
    }
  }
}

// ================= GEMM2: 256x128, K=4096, 2-phase/K-tile interleave, counted vmcnt =========
template <int OST>
__global__ __launch_bounds__(512, 1) void gemm2_pipe_kernel(
    const __hip_bfloat16* __restrict__ mid, const __hip_bfloat16* __restrict__ wd9,
    float* __restrict__ mid2, float* __restrict__ y,
    const int* __restrict__ rowlist, const float* __restrict__ roww,
    const int* __restrict__ ecnt, const int* __restrict__ tile_map,
    const int* __restrict__ ntiles, const float* __restrict__ ssc,
    int mode, int tile_base)
{
  constexpr int K = HDIM;
  constexpr int NTL = K / 64;                   // 64 K-tiles
  __shared__ __align__(16) short lds[49152];    // A: 2x16384 @0, B: 2x8192 @32768 (96 KB)

  int ti = blockIdx.y + tile_base;
  if (mode == 2) ti += ntiles[0];
  const int hi = (mode == 1) ? ntiles[0] : ntiles[1];
  if (ti >= hi) return;
  const int tm = tile_map[ti];
  const int e = tm & 15, rb = tm >> 4;
  const int rows_valid = ecnt[e] - rb;
  const int gbmid = (int)blockIdx.y * 256;
  const int glist = ti * 256;

  const int t = threadIdx.x, l = t & 63, w = t >> 6;
  const int wr = w >> 2, wc = w & 3;            // 2M x 4N waves, 128x32 out per wave
  const int n0 = blockIdx.x * 128;

  const int rbase = w * 8 + (l >> 3);
  const int ksrc = ((l & 7) ^ ((l >> 3) & 7)) * 8;
  const short* pA[4]; const short* pB[2];
#pragma unroll
  for (int j = 0; j < 4; ++j)
    pA[j] = (const short*)mid + (size_t)(gbmid + j * 64 + rbase) * K + ksrc;
#pragma unroll
  for (int j = 0; j < 2; ++j)
    pB[j] = (const short*)wd9 + (size_t)e * CDIM * HDIM + (size_t)(n0 + j * 64 + rbase) * K + ksrc;
  const int dst0 = w * 512 + l * 8;

#define STG2_AH(tt, h) { const int b_ = ((tt) & 1) * 16384; \
    gload16(pA[2*(h)]   + (size_t)(tt) * 64, lds + b_ + (2*(h)) * 4096   + dst0); \
    gload16(pA[2*(h)+1] + (size_t)(tt) * 64, lds + b_ + (2*(h)+1) * 4096 + dst0); }
#define STG2_B(tt) { const int b_ = 32768 + ((tt) & 1) * 8192; \
    gload16(pB[0] + (size_t)(tt) * 64, lds + b_ + dst0); \
    gload16(pB[1] + (size_t)(tt) * 64, lds + b_ + 4096 + dst0); }

  const int l15 = l & 15;
  const int cs0 = (((l >> 4)) ^ (l & 7)) * 8;
  const int cs1 = ((4 + (l >> 4)) ^ (l & 7)) * 8;
  const int afb = (wr * 128 + l15) * 64;
  const int bfb = (wc * 32 + l15) * 64;

  f32x4 acc[8][2];
#pragma unroll
  for (int i = 0; i < 8; ++i) { acc[i][0] = (f32x4){0.f,0.f,0.f,0.f}; acc[i][1] = (f32x4){0.f,0.f,0.f,0.f}; }

  short8 af[4][2], bf[2][2];

  STG2_AH(0, 0) STG2_AH(0, 1) STG2_B(0)

  for (int tt = 0; tt < NTL; ++tt) {
    const int ab = (tt & 1) * 16384, bb = 32768 + (tt & 1) * 8192;
    // ---- boundary ----
    if (tt + 1 < NTL) {
      STG2_AH(tt + 1, 0)
      asm volatile("s_waitcnt vmcnt(2)\n\ts_barrier" ::: "memory");
    } else {
      asm volatile("s_waitcnt vmcnt(0)\n\ts_barrier" ::: "memory");
    }
    __builtin_amdgcn_sched_barrier(0);
    // ---- phase A: mi0-3 ----
#pragma unroll
    for (int mi = 0; mi < 4; ++mi) {
      af[mi][0] = *(const short8*)(lds + ab + afb + mi * 1024 + cs0);
      af[mi][1] = *(const short8*)(lds + ab + afb + mi * 1024 + cs1);
    }
#pragma unroll
    for (int ni = 0; ni < 2; ++ni) {
      bf[ni][0] = *(const short8*)(lds + bb + bfb + ni * 1024 + cs0);
      bf[ni][1] = *(const short8*)(lds + bb + bfb + ni * 1024 + cs1);
    }
    if (tt + 1 < NTL) STG2_AH(tt + 1, 1)
    BAR; LGKM0;
    __builtin_amdgcn_s_setprio(1);
#pragma unroll
    for (int ks = 0; ks < 2; ++ks)
#pragma unroll
      for (int mi = 0; mi < 4; ++mi)
#pragma unroll
        for (int ni = 0; ni < 2; ++ni)
          acc[mi][ni] = __builtin_amdgcn_mfma_f32_16x16x32_bf16(af[mi][ks], bf[ni][ks], acc[mi][ni], 0, 0, 0);
    __builtin_amdgcn_s_setprio(0);
    BAR;
    // ---- phase B: mi4-7 ----
#pragma unroll
    for (int mi = 0; mi < 4; ++mi) {
      af[mi][0] = *(const short8*)(lds + ab + afb + 4096 + mi * 1024 + cs0);
      af[mi][1] = *(const short8*)(lds + ab + afb + 4096 + mi * 1024 + cs1);
    }
    if (tt + 1 < NTL) STG2_B(tt + 1)
    BAR; LGKM0;
    __builtin_amdgcn_s_setprio(1);
#pragma unroll
    for (int ks = 0; ks < 2; ++ks)
#pragma unroll
      for (int mi = 0; mi < 4; ++mi)
#pragma unroll
        for (int ni = 0; ni < 2; ++ni)
          acc[4 + mi][ni] = __builtin_amdgcn_mfma_f32_16x16x32_bf16(af[mi][ks], bf[ni][ks], acc[4 + mi][ni], 0, 0, 0);
    __builtin_amdgcn_s_setprio(0);
    BAR;
  }
#undef STG2_AH
#undef STG2_B

  const int rl = (l >> 4) * 4, cl = l & 15;
  if (OST) {
#pragma unroll
    for (int mi = 0; mi < 8; ++mi) {
#pragma unroll
      for (int j = 0; j < 4; ++j) {
        const int rlocal = wr * 128 + mi * 16 + rl + j;
        if (rlocal < rows_valid) {
          float* mp = mid2 + (size_t)(glist + rlocal) * CDIM + n0 + wc * 32 + cl;
          mp[0]  = acc[mi][0][j];
          mp[16] = acc[mi][1][j];
        }
      }
    }
  } else {
    const float ss = ssc[0];
#pragma unroll
    for (int mi = 0; mi < 8; ++mi) {
#pragma unroll
      for (int j = 0; j < 4; ++j) {
        const int rlocal = wr * 128 + mi * 16 + rl + j;
        if (rlocal < rows_valid) {
          int tok; float wgt;
          if (e == 8) { tok = rb + rlocal; wgt = ss; }
          else { tok = rowlist[glist + rlocal]; wgt = roww[glist + rlocal]; }
          float* yp = y + (size_t)tok * CDIM + n0 + wc * 32 + cl;
          unsafeAtomicAdd(yp,      wgt * acc[mi][0][j]);
          unsafeAtomicAdd(yp + 16, wgt * acc[mi][1][j]);
        }
      }
    }
  }
}

// ---------------- combine ----------------
__global__ __launch_bounds__(256) void combine_kernel(
    const float* __restrict__ mid2, const int* __restrict__ ntiles,
    const int2* __restrict__ tokpos, const float* __restrict__ tokw,
    const float* __restrict__ ssc, float* __restrict__ y)
{
  const int t = blockIdx.x;
  const int c = threadIdx.x * 4;
  const int dbase = ntiles[0] * 256;
  const int2 gp = tokpos[t];
  const float2 wv = ((const float2*)tokw)[t];
  const float ss = ssc[0];
  const float4 d = *(const float4*)(mid2 + (size_t)(dbase + t) * CDIM + c);
  const float4 a = *(const float4*)(mid2 + (size_t)gp.x * CDIM + c);
  const float4 b = *(const float4*)(mid2 + (size_t)gp.y * CDIM + c);
  float4 r;
  r.x = ss * d.x + wv.x * a.x + wv.y * b.x;
  r.y = ss * d.y + wv.x * a.y + wv.y * b.y;
  r.z = ss * d.z + wv.x * a.z + wv.y * b.z;
  r.w = ss * d.w + wv.x * a.w + wv.y * b.w;
  *(float4*)(y + (size_t)t * CDIM + c) = r;
}

// ---------------- host ----------------
extern "C" void kernel_launch(void* const* d_in, const int* in_sizes, int n_in,
                              void* d_out, int out_size, void* d_ws, size_t ws_size,
                              hipStream_t stream)
{
  const float* x   = (const float*)d_in[0];
  const float* gw  = (const float*)d_in[1];
  const float* wg  = (const float*)d_in[2];
  const float* wu  = (const float*)d_in[3];
  const float* wd  = (const float*)d_in[4];
  const float* swg = (const float*)d_in[5];
  const float* swu = (const float*)d_in[6];
  const float* swd = (const float*)d_in[7];
  const float* ssc = (const float*)d_in[8];
  float* y = (float*)d_out;

  auto al = [](size_t v) { return (v + 255) & ~(size_t)255; };
  char* ws = (char*)d_ws;
  size_t off = 0;
  __hip_bfloat16* xb = (__hip_bfloat16*)(ws + off); off += al((size_t)T_TOK * CDIM * 2);
  int*   tokinfo = (int*)(ws + off);   off += al((size_t)T_TOK * 4);
  float* tokw    = (float*)(ws + off); off += al((size_t)T_TOK * 8);
  int2*  tokpos  = (int2*)(ws + off);  off += al((size_t)T_TOK * 8);
  int*   bcnt    = (int*)(ws + off);   off += al((size_t)(T_TOK / 4) * NEXP * 4);
  int*   boffb   = (int*)(ws + off);   off += al((size_t)(T_TOK / 4) * NEXP * 4);
  float* spart   = (float*)(ws + off); off += al((size_t)(T_TOK / 4) * NEXP * 4);
  int*   ecnt    = (int*)(ws + off);   off += 256;   // 9 used
  int*   pad_off = (int*)(ws + off);   off += 256;
  int*   ntiles  = (int*)(ws + off);   off += 256;
  int*   tile_map= (int*)(ws + off);   off += al((size_t)UT_MAX * 4);
  int*   grows   = (int*)(ws + off);   off += al((size_t)GROWS_MAX * 4);
  float* gww     = (float*)(ws + off); off += al((size_t)GROWS_MAX * 4);

  const size_t WMAT = (size_t)CDIM * HDIM;
  __hip_bfloat16* wg9 = (__hip_bfloat16*)(ws + off); off += 9 * WMAT * 2;
  __hip_bfloat16* wu9 = (__hip_bfloat16*)(ws + off); off += 9 * WMAT * 2;
  __hip_bfloat16* wd9 = (__hip_bfloat16*)(ws + off); off += 9 * WMAT * 2;
  __hip_bfloat16* mid = (__hip_bfloat16*)(ws + off);
  const size_t mid_avail = (ws_size > off) ? (ws_size - off) : 0;
  const size_t TILE_B = (size_t)256 * HDIM * 2;                 // 2 MB per 256-row mid tile
  const size_t MIDB   = (size_t)UT_MAX * TILE_B;                // bf16 mid (full)
  const size_t MID2B  = (size_t)UT_MAX * 256 * CDIM * 4;        // fp32 partials

  gate_kernel<<<T_TOK / 4, 256, 0, stream>>>(x, gw, tokinfo, tokw, bcnt, spart, xb);
  scan_kernel<<<1, 512, 0, stream>>>(bcnt, boffb, ecnt, spart, y + (size_t)T_TOK * CDIM,
                                     pad_off, tile_map, ntiles);
  scatter_kernel<<<T_TOK / 256, 256, 0, stream>>>(tokinfo, tokw, boffb, pad_off,
                                                  grows, gww, tokpos);

  TB tb;
  for (int e = 0; e < 8; ++e) {
    tb.d[e]      = TD{wg + e * WMAT, wg9 + e * WMAT, HDIM, 7, CDIM};
    tb.d[8 + e]  = TD{wu + e * WMAT, wu9 + e * WMAT, HDIM, 7, CDIM};
    tb.d[16 + e] = TD{wd + e * WMAT, wd9 + e * WMAT, CDIM, 5, HDIM};
  }
  tb.d[24] = TD{swg, wg9 + 8 * WMAT, HDIM, 7, CDIM};
  tb.d[25] = TD{swu, wu9 + 8 * WMAT, HDIM, 7, CDIM};
  tb.d[26] = TD{swd, wd9 + 8 * WMAT, CDIM, 5, HDIM};
  tbatch_kernel<<<27 * 4096, 256, 0, stream>>>(tb);

  if (mid_avail >= MIDB + MID2B) {
    float* mid2 = (float*)((char*)mid + MIDB);
    gemm1_pipe_kernel<<<dim3(HDIM / 128, UT_MAX), 512, 0, stream>>>(
        xb, wg9, wu9, mid, grows, ecnt, tile_map, ntiles, 0, 0);
    gemm2_pipe_kernel<1><<<dim3(CDIM / 128, UT_MAX), 512, 0, stream>>>(
        mid, wd9, mid2, nullptr, grows, gww, ecnt, tile_map, ntiles, ssc, 0, 0);
    combine_kernel<<<T_TOK, 256, 0, stream>>>(mid2, ntiles, tokpos, tokw, ssc, y);
  } else if (mid_avail >= MIDB) {
    hipMemsetAsync(y, 0, (size_t)T_TOK * CDIM * sizeof(float), stream);
    gemm1_pipe_kernel<<<dim3(HDIM / 128, UT_MAX), 512, 0, stream>>>(
        xb, wg9, wu9, mid, grows, ecnt, tile_map, ntiles, 0, 0);
    gemm2_pipe_kernel<0><<<dim3(CDIM / 128, UT_MAX), 512, 0, stream>>>(
        mid, wd9, nullptr, y, grows, gww, ecnt, tile_map, ntiles, ssc, 0, 0);
  } else {
    hipMemsetAsync(y, 0, (size_t)T_TOK * CDIM * sizeof(float), stream);
    int CH = (int)(mid_avail / TILE_B);
    if (CH < 1) CH = 1;
    for (int c0 = 0; c0 < GT_MAX; c0 += CH) {
      const int g = (GT_MAX - c0) < CH ? (GT_MAX - c0) : CH;
      gemm1_pipe_kernel<<<dim3(HDIM / 128, g), 512, 0, stream>>>(
          xb, wg9, wu9, mid, grows, ecnt, tile_map, ntiles, 1, c0);
      gemm2_pipe_kernel<0><<<dim3(CDIM / 128, g), 512, 0, stream>>>(
          mid, wd9, nullptr, y, grows, gww, ecnt, tile_map, ntiles, ssc, 1, c0);
    }
    for (int c0 = 0; c0 < 32; c0 += CH) {
      const int g = (32 - c0) < CH ? (32 - c0) : CH;
      gemm1_pipe_kernel<<<dim3(HDIM / 128, g), 512, 0, stream>>>(
          xb, wg9, wu9, mid, grows, ecnt, tile_map, ntiles, 2, c0);
      gemm2_pipe_kernel<0><<<dim3(CDIM / 128, g), 512, 0, stream>>>(
          mid, wd9, nullptr, y, grows, gww, ecnt, tile_map, ntiles, ssc, 2, c0);
    }
  }
}